// Round 1
// 1600.954 us; speedup vs baseline: 1.0564x; 1.0564x over previous
//
#include <hip/hip_runtime.h>
#include <math.h>

namespace {

constexpr int Bn  = 16;
constexpr int Cn  = 256;
constexpr int C8n = 32;

typedef __attribute__((ext_vector_type(8))) __bf16 bf16x8;
typedef __attribute__((ext_vector_type(4))) __bf16 bf16x4;
typedef __attribute__((ext_vector_type(4))) float  floatx4;

// ---------------------------------------------------------------------------
// fp32 q/k projection (unchanged).
// grid: (Npix/128, B), block 256.
// ---------------------------------------------------------------------------
__global__ __launch_bounds__(256) void qk_proj_kernel(
    const float* __restrict__ x,      // [B][C][Npix]
    const float* __restrict__ qw,     // [C8][C]
    const float* __restrict__ qbias,  // [C8]
    const float* __restrict__ kw,
    const float* __restrict__ kbias,
    float* __restrict__ qo,           // [B][C8][Npix]
    float* __restrict__ ko,
    int Npix)
{
    __shared__ float xs[64][128];
    __shared__ float ws[64][68];
    const int t  = threadIdx.x;
    const int b  = blockIdx.y;
    const int p0 = blockIdx.x * 128;
    const int tx = t & 31;
    const int ty = t >> 5;
    float acc[8][4];
#pragma unroll
    for (int i = 0; i < 8; ++i)
#pragma unroll
        for (int j = 0; j < 4; ++j) acc[i][j] = 0.f;

    const float* xb  = x + (size_t)b * Cn * Npix;
    const int skk = t & 63, sor = t >> 6;

    for (int k0 = 0; k0 < Cn; k0 += 64) {
#pragma unroll
        for (int r = 0; r < 8; ++r) {
            int idx = r * 256 + t;
            int kk = idx >> 5, pp = (idx & 31) * 4;
            *(float4*)&xs[kk][pp] =
                *(const float4*)&xb[(size_t)(k0 + kk) * Npix + p0 + pp];
        }
#pragma unroll
        for (int r = 0; r < 16; ++r) {
            int o = r * 4 + sor;
            const float* wsrc = (o < 32) ? (qw + (size_t)o * Cn)
                                         : (kw + (size_t)(o - 32) * Cn);
            ws[skk][o] = wsrc[k0 + skk];
        }
        __syncthreads();
#pragma unroll 4
        for (int kk = 0; kk < 64; ++kk) {
            float4 w0 = *(const float4*)&ws[kk][ty * 8];
            float4 w1 = *(const float4*)&ws[kk][ty * 8 + 4];
            float4 xv = *(const float4*)&xs[kk][tx * 4];
            float wv[8] = {w0.x, w0.y, w0.z, w0.w, w1.x, w1.y, w1.z, w1.w};
            float pv[4] = {xv.x, xv.y, xv.z, xv.w};
#pragma unroll
            for (int i = 0; i < 8; ++i)
#pragma unroll
                for (int j = 0; j < 4; ++j)
                    acc[i][j] = fmaf(wv[i], pv[j], acc[i][j]);
        }
        __syncthreads();
    }
#pragma unroll
    for (int i = 0; i < 8; ++i) {
        int o = ty * 8 + i;
        float bias;
        float* dst;
        if (o < 32) { bias = qbias[o];      dst = qo + ((size_t)b * C8n + o)        * Npix; }
        else        { bias = kbias[o - 32]; dst = ko + ((size_t)b * C8n + (o - 32)) * Npix; }
        float4 v4 = make_float4(acc[i][0] + bias, acc[i][1] + bias,
                                acc[i][2] + bias, acc[i][3] + bias);
        *(float4*)&dst[p0 + tx * 4] = v4;
    }
}

// ---------------------------------------------------------------------------
// fp32 energy over W (unchanged). grid ((P/64)^2, B, 8).
// ---------------------------------------------------------------------------
__global__ __launch_bounds__(256) void energy_w_kernel(
    const float* __restrict__ q, const float* __restrict__ k,
    float* __restrict__ epart, int P, int KL)
{
    __shared__ float qs[32][64];
    __shared__ float ks[32][64];
    const int t  = threadIdx.x;
    const int nt = P >> 6;
    const int tw = blockIdx.x / nt;
    const int tv = blockIdx.x % nt;
    const int b  = blockIdx.y;
    const int z  = blockIdx.z;
    const int w0 = tw * 64, v0 = tv * 64;
    const int Ktot = KL * 8;
    const float* qb = q + ((size_t)b * Ktot + (size_t)z * KL) * P;
    const float* kb = k + ((size_t)b * Ktot + (size_t)z * KL) * P;
    const int tx = t & 15, ty = t >> 4;
    float acc[4][4];
#pragma unroll
    for (int i = 0; i < 4; ++i)
#pragma unroll
        for (int j = 0; j < 4; ++j) acc[i][j] = 0.f;

    for (int kc = 0; kc < KL; kc += 32) {
#pragma unroll
        for (int r = 0; r < 8; ++r) {
            int idx = r * 256 + t;
            int kk = idx >> 6, col = idx & 63;
            qs[kk][col] = qb[(size_t)(kc + kk) * P + w0 + col];
            ks[kk][col] = kb[(size_t)(kc + kk) * P + v0 + col];
        }
        __syncthreads();
#pragma unroll 8
        for (int kk = 0; kk < 32; ++kk) {
            float4 qv = *(const float4*)&qs[kk][ty * 4];
            float4 kv = *(const float4*)&ks[kk][tx * 4];
            float qa[4] = {qv.x, qv.y, qv.z, qv.w};
            float ka[4] = {kv.x, kv.y, kv.z, kv.w};
#pragma unroll
            for (int i = 0; i < 4; ++i)
#pragma unroll
                for (int j = 0; j < 4; ++j)
                    acc[i][j] = fmaf(qa[i], ka[j], acc[i][j]);
        }
        __syncthreads();
    }
#pragma unroll
    for (int i = 0; i < 4; ++i) {
        size_t off = (((size_t)z * Bn + b) * P + (w0 + ty * 4 + i)) * P + v0 + tx * 4;
        *(float4*)&epart[off] = make_float4(acc[i][0], acc[i][1], acc[i][2], acc[i][3]);
    }
}

// ---------------------------------------------------------------------------
// fp32 energy over H (unchanged). grid ((P/64)^2, B, 8).
// ---------------------------------------------------------------------------
__global__ __launch_bounds__(256) void energy_h_kernel(
    const float* __restrict__ q, const float* __restrict__ k,
    float* __restrict__ epart, int P)
{
    __shared__ float qsT[64][68];
    __shared__ float ksT[64][68];
    const int t  = threadIdx.x;
    const int nt = P >> 6;
    const int th = blockIdx.x / nt;
    const int tv = blockIdx.x % nt;
    const int b  = blockIdx.y;
    const int z  = blockIdx.z;
    const int h0 = th * 64, v0 = tv * 64;
    const int o0 = z * (C8n / 8);
    const int tx = t & 15, ty = t >> 4;
    const int ww = t & 63, hh0 = t >> 6;
    float acc[4][4];
#pragma unroll
    for (int i = 0; i < 4; ++i)
#pragma unroll
        for (int j = 0; j < 4; ++j) acc[i][j] = 0.f;

    for (int o = o0; o < o0 + 4; ++o) {
        const float* qo = q + ((size_t)(b * C8n + o)) * P * P;
        const float* ko = k + ((size_t)(b * C8n + o)) * P * P;
        for (int wc = 0; wc < P; wc += 64) {
#pragma unroll
            for (int r = 0; r < 16; ++r) {
                int hh = r * 4 + hh0;
                qsT[ww][hh] = qo[(size_t)(h0 + hh) * P + wc + ww];
                ksT[ww][hh] = ko[(size_t)(v0 + hh) * P + wc + ww];
            }
            __syncthreads();
#pragma unroll 8
            for (int kk = 0; kk < 64; ++kk) {
                float4 qv = *(const float4*)&qsT[kk][ty * 4];
                float4 kv = *(const float4*)&ksT[kk][tx * 4];
                float qa[4] = {qv.x, qv.y, qv.z, qv.w};
                float ka[4] = {kv.x, kv.y, kv.z, kv.w};
#pragma unroll
                for (int i = 0; i < 4; ++i)
#pragma unroll
                    for (int j = 0; j < 4; ++j)
                        acc[i][j] = fmaf(qa[i], ka[j], acc[i][j]);
            }
            __syncthreads();
        }
    }
#pragma unroll
    for (int i = 0; i < 4; ++i) {
        size_t off = (((size_t)z * Bn + b) * P + (h0 + ty * 4 + i)) * P + v0 + tx * 4;
        *(float4*)&epart[off] = make_float4(acc[i][0], acc[i][1], acc[i][2], acc[i][3]);
    }
}

// ---------------------------------------------------------------------------
// Row softmax with split-K reduction; bf16 output (unchanged).
// grid: B*P, block 64.
// ---------------------------------------------------------------------------
template <int P>
__global__ __launch_bounds__(64) void softmax_kernel(
    const float* __restrict__ epart,  // [8][B][P][P]
    __bf16* __restrict__ a)           // [B][P][P] bf16
{
    const int row  = blockIdx.x;
    const int lane = threadIdx.x;
    constexpr int E = P / 64;
    float e[E];
#pragma unroll
    for (int j = 0; j < E; ++j) {
        int v = lane + j * 64;
        float s = 0.f;
#pragma unroll
        for (int z = 0; z < 8; ++z)
            s += epart[((size_t)z * Bn * P + row) * P + v];
        e[j] = s;
    }
    float m = e[0];
#pragma unroll
    for (int j = 1; j < E; ++j) m = fmaxf(m, e[j]);
    for (int off = 32; off > 0; off >>= 1) m = fmaxf(m, __shfl_xor(m, off));
    float sum = 0.f;
#pragma unroll
    for (int j = 0; j < E; ++j) { e[j] = __expf(e[j] - m); sum += e[j]; }
    for (int off = 32; off > 0; off >>= 1) sum += __shfl_xor(sum, off);
    float inv = 1.0f / sum;
#pragma unroll
    for (int j = 0; j < E; ++j)
        a[(size_t)row * P + lane + j * 64] = (__bf16)(e[j] * inv);
}

// ---------------------------------------------------------------------------
// Transpose for the H-branch (unchanged).
// ---------------------------------------------------------------------------
__global__ __launch_bounds__(256) void transpose_h_kernel(
    const float* __restrict__ x, __bf16* __restrict__ xh, int P)
{
    __shared__ float tile[32][33];
    const int tpb = P >> 5;
    const int tw = blockIdx.x % tpb, th = blockIdx.x / tpb;
    const int c = blockIdx.y, b = blockIdx.z;
    const float* src = x + ((size_t)(b * Cn + c)) * P * P;
    const int i  = threadIdx.x >> 3;
    const int j4 = (threadIdx.x & 7) * 4;
    float4 v = *(const float4*)&src[(size_t)(th * 32 + i) * P + tw * 32 + j4];
    tile[i][j4 + 0] = v.x; tile[i][j4 + 1] = v.y;
    tile[i][j4 + 2] = v.z; tile[i][j4 + 3] = v.w;
    __syncthreads();
    __bf16* dst = xh + ((size_t)(b * P + tw * 32 + i) * Cn + c) * P + th * 32 + j4;
    bf16x4 o = { (__bf16)tile[j4 + 0][i], (__bf16)tile[j4 + 1][i],
                 (__bf16)tile[j4 + 2][i], (__bf16)tile[j4 + 3][i] };
    *(bf16x4*)dst = o;
}

// ---------------------------------------------------------------------------
// vw fp32 -> bf16 convert (unchanged).
// ---------------------------------------------------------------------------
__global__ __launch_bounds__(256) void cvt_vw_kernel(
    const float* __restrict__ vw, __bf16* __restrict__ vwb)
{
    int i4 = blockIdx.x * 256 + threadIdx.x;
    float4 v = *(const float4*)&vw[(size_t)i4 * 4];
    bf16x4 o = { (__bf16)v.x, (__bf16)v.y, (__bf16)v.z, (__bf16)v.w };
    *(bf16x4*)&vwb[(size_t)i4 * 4] = o;
}

// ---------------------------------------------------------------------------
// MFMA mix — NOW register-staged + double-buffered LDS (one barrier/K-step).
// Next K-tile's global loads are issued right after the barrier so their
// ~900-cy latency hides under the current tile's ds_read + 16 MFMA.
// Math, layouts, grids and the epilogue are identical to the prior version.
// grid: ((P/BM)*(C/BN), B*P), block 256.
// ---------------------------------------------------------------------------
template <int P, int BM, int BN, int MODE>
__global__ __launch_bounds__(256) void mix_mfma_kernel(
    const __bf16* __restrict__ abf,  // [B][P][P]
    const float*  __restrict__ x,    // [B][C][P][P]
    const __bf16* __restrict__ xh,   // [B][P][C][P]
    __bf16* __restrict__ yt)         // [B][P*P][C]
{
    constexpr int BK  = 32;
    constexpr int LDA = BK + 8;   // 40 bf16 = 80 B rows (conflict-min for b128)
    constexpr int WNn = BN / 64;
    constexpr int ACH = BM / 64;  // A staging chunks per thread
    constexpr int BCH = BN / 64;  // B staging chunks per thread
    constexpr int NT  = P / BK;   // K-steps
    __shared__ __bf16 As[2][BM][LDA];
    __shared__ __bf16 Bs[2][BN][LDA];
    __shared__ __bf16 Es[4][16][72];
    const int t = threadIdx.x;
    const int z = blockIdx.y;
    const int b = z / P, j = z % P;
    const int mt = blockIdx.x / (Cn / BN);
    const int nt = blockIdx.x % (Cn / BN);
    const int m0 = mt * BM, n0 = nt * BN;
    const int wave = t >> 6, lane = t & 63;
    const int wm = (wave / WNn) * 64, wn = (wave % WNn) * 64;
    const int l16 = lane & 15, quad = lane >> 4;
    const int crow = t >> 2, cpart = (t & 3) * 8;  // per-thread staging slot

    floatx4 acc[4][4] = {};

    const __bf16* Ab = abf + (size_t)b * P * P + (size_t)m0 * P;

    uint4  aR[ACH];
    float4 bRa[BCH], bRb[BCH];   // MODE 0 staging (fp32, convert at ds_write)
    uint4  bRu[BCH];             // MODE 1 staging (bf16 passthrough)

    auto load_tile = [&](int kc) {
#pragma unroll
        for (int r = 0; r < ACH; ++r) {
            int row = r * 64 + crow;
            aR[r] = *(const uint4*)&Ab[(size_t)row * P + kc + cpart];
        }
#pragma unroll
        for (int r = 0; r < BCH; ++r) {
            int row = r * 64 + crow;
            if (MODE == 0) {
                const float* src =
                    x + ((size_t)(b * Cn + n0 + row) * P + j) * P + kc + cpart;
                bRa[r] = *(const float4*)&src[0];
                bRb[r] = *(const float4*)&src[4];
            } else {
                bRu[r] = *(const uint4*)&xh[((size_t)(b * P + j) * Cn + n0 + row) * P + kc + cpart];
            }
        }
    };
    auto store_tile = [&](int buf) {
#pragma unroll
        for (int r = 0; r < ACH; ++r)
            *(uint4*)&As[buf][r * 64 + crow][cpart] = aR[r];
#pragma unroll
        for (int r = 0; r < BCH; ++r) {
            if (MODE == 0) {
                bf16x8 o = { (__bf16)bRa[r].x, (__bf16)bRa[r].y,
                             (__bf16)bRa[r].z, (__bf16)bRa[r].w,
                             (__bf16)bRb[r].x, (__bf16)bRb[r].y,
                             (__bf16)bRb[r].z, (__bf16)bRb[r].w };
                *(bf16x8*)&Bs[buf][r * 64 + crow][cpart] = o;
            } else {
                *(uint4*)&Bs[buf][r * 64 + crow][cpart] = bRu[r];
            }
        }
    };

    load_tile(0);
#pragma unroll
    for (int it = 0; it < NT; ++it) {
        const int buf = it & 1;
        store_tile(buf);
        __syncthreads();
        if (it < NT - 1) load_tile((it + 1) * BK);  // in flight during MFMA
        bf16x8 af[4], bfr[4];
#pragma unroll
        for (int i = 0; i < 4; ++i)
            af[i] = *(const bf16x8*)&As[buf][wm + i * 16 + l16][quad * 8];
#pragma unroll
        for (int j2 = 0; j2 < 4; ++j2)
            bfr[j2] = *(const bf16x8*)&Bs[buf][wn + j2 * 16 + l16][quad * 8];
#pragma unroll
        for (int i = 0; i < 4; ++i)
#pragma unroll
            for (int j2 = 0; j2 < 4; ++j2)
                acc[i][j2] = __builtin_amdgcn_mfma_f32_16x16x32_bf16(
                    af[i], bfr[j2], acc[i][j2], 0, 0, 0);
        // no second barrier: next iteration writes the OTHER buffer, and
        // this barrier already ordered everyone's reads of it.
    }

    // Epilogue: repack each wave's 16x64 row-group through LDS, store bf16x8.
    const size_t outB = (size_t)b * P * P * Cn;
#pragma unroll
    for (int i = 0; i < 4; ++i) {
#pragma unroll
        for (int j2 = 0; j2 < 4; ++j2)
#pragma unroll
            for (int r = 0; r < 4; ++r)
                Es[wave][quad * 4 + r][j2 * 16 + l16] = (__bf16)acc[i][j2][r];
        // wave-private LDS; per-wave DS ordering makes this safe without barrier
#pragma unroll
        for (int s2 = 0; s2 < 2; ++s2) {
            int ch = s2 * 64 + lane;
            int row = ch >> 3, part = ch & 7;
            bf16x8 v = *(const bf16x8*)&Es[wave][row][part * 8];
            int m = m0 + wm + i * 16 + row;
            size_t rowOff = (MODE == 0) ? (size_t)(j * P + m) : ((size_t)m * P + j);
            *(bf16x8*)&yt[outB + rowOff * Cn + n0 + wn + part * 8] = v;
        }
    }
}

// ---------------------------------------------------------------------------
// MFMA v-projection + scale + bias + residual epilogue — REWRITTEN:
//   * register-staged double-buffered LDS K-loop, ONE barrier per K-step,
//     next tile's loads issued before the MFMAs (latency hidden under compute)
//   * epilogue repacked through LDS (reusing staging LDS) so out/x are
//     accessed as float4 with 256 B contiguous per 16-lane phase
// out[c][p] = (first? 2x : out) + s*(sum_k vw[c][k]*Y_T[p][k] + vb[c])
// grid: (Npix/128, 2, B), block 256 (4 waves, each 64x64 of the 128x128 tile).
// ---------------------------------------------------------------------------
__global__ __launch_bounds__(256, 3) void vproj_mfma_kernel(
    const __bf16* __restrict__ yt,   // [B][Npix][C]
    const __bf16* __restrict__ vwb,  // [C][C]
    const float* __restrict__ vb,
    const float* __restrict__ x,
    float* __restrict__ out,
    const float* __restrict__ scal, int si, int first, int Npix)
{
    // 40960 B: [2][128][40] bf16 A + [2][128][40] bf16 B, reused as fp32
    // epilogue scratch (4 waves x 16 x 68 fp32 = 17408 B) after the K loop.
    __shared__ __align__(16) char smraw[40960];
    __bf16 (*As)[128][40]  = (__bf16(*)[128][40])(smraw);
    __bf16 (*Bsm)[128][40] = (__bf16(*)[128][40])(smraw + 20480);

    const int t  = threadIdx.x;
    const int p0 = blockIdx.x * 128;
    const int c0 = blockIdx.y * 128;
    const int b  = blockIdx.z;
    const int wave = t >> 6, lane = t & 63;
    const int wm = (wave >> 1) * 64, wn = (wave & 1) * 64;
    const int l16 = lane & 15, quad = lane >> 4;
    const int crow = t >> 2, cpart = (t & 3) * 8;
    floatx4 acc[4][4] = {};
    const __bf16* Ab = vwb + (size_t)c0 * Cn;
    const __bf16* Bb = yt + ((size_t)b * Npix + p0) * Cn;

    uint4 aR0, aR1, bR0, bR1;
    auto load_tile = [&](int kc) {
        aR0 = *(const uint4*)&Ab[(size_t)crow * Cn + kc + cpart];
        aR1 = *(const uint4*)&Ab[(size_t)(crow + 64) * Cn + kc + cpart];
        bR0 = *(const uint4*)&Bb[(size_t)crow * Cn + kc + cpart];
        bR1 = *(const uint4*)&Bb[(size_t)(crow + 64) * Cn + kc + cpart];
    };

    load_tile(0);
#pragma unroll
    for (int it = 0; it < 8; ++it) {
        const int buf = it & 1;
        *(uint4*)&As[buf][crow][cpart]       = aR0;
        *(uint4*)&As[buf][crow + 64][cpart]  = aR1;
        *(uint4*)&Bsm[buf][crow][cpart]      = bR0;
        *(uint4*)&Bsm[buf][crow + 64][cpart] = bR1;
        __syncthreads();
        if (it < 7) load_tile((it + 1) * 32);  // in flight during MFMA
        bf16x8 af[4], bfr[4];
#pragma unroll
        for (int i = 0; i < 4; ++i)
            af[i] = *(const bf16x8*)&As[buf][wm + i * 16 + l16][quad * 8];
#pragma unroll
        for (int j2 = 0; j2 < 4; ++j2)
            bfr[j2] = *(const bf16x8*)&Bsm[buf][wn + j2 * 16 + l16][quad * 8];
#pragma unroll
        for (int i = 0; i < 4; ++i)
#pragma unroll
            for (int j2 = 0; j2 < 4; ++j2)
                acc[i][j2] = __builtin_amdgcn_mfma_f32_16x16x32_bf16(
                    af[i], bfr[j2], acc[i][j2], 0, 0, 0);
        // single barrier per K-step: next iter writes the other buffer.
    }
    __syncthreads();  // staging LDS is about to be reused as fp32 scratch

    // Epilogue: per wave, repack each 16(c) x 64(pix) fragment group through
    // LDS, then float4 read-modify-write of out (256 B contiguous per phase).
    const float s = scal[si];
    float* ewp = (float*)smraw + wave * (16 * 68);  // 4352 B per wave
#pragma unroll
    for (int i = 0; i < 4; ++i) {
#pragma unroll
        for (int j2 = 0; j2 < 4; ++j2)
#pragma unroll
            for (int r = 0; r < 4; ++r)
                ewp[(quad * 4 + r) * 68 + j2 * 16 + l16] = acc[i][j2][r];
        // wave-private LDS; per-wave DS ordering makes this safe without barrier
#pragma unroll
        for (int u = 0; u < 4; ++u) {
            int idx = u * 64 + lane;
            int rr = idx >> 4, col = (idx & 15) * 4;
            float4 v = *(const float4*)&ewp[rr * 68 + col];
            int c = c0 + wm + i * 16 + rr;
            float bias = vb[c];
            size_t g = ((size_t)(b * Cn + c)) * Npix + p0 + wn + col;
            float4 prev;
            if (first) {
                float4 xv = *(const float4*)&x[g];
                prev = make_float4(2.f * xv.x, 2.f * xv.y, 2.f * xv.z, 2.f * xv.w);
            } else {
                prev = *(const float4*)&out[g];
            }
            float4 res = make_float4(s * (v.x + bias) + prev.x,
                                     s * (v.y + bias) + prev.y,
                                     s * (v.z + bias) + prev.z,
                                     s * (v.w + bias) + prev.w);
            *(float4*)&out[g] = res;
        }
    }
}

struct Bufs {
    __bf16* XH;   // [16][128][256][128] bf16  = 134,217,728 B
    __bf16* YT;   // [16][16384][256]    bf16  = 134,217,728 B (q,k alias head)
    float*  E;    // [8][16][128][128]   fp32  =   8,388,608 B
    __bf16* ABF;  // [16][128][128]      bf16  =     524,288 B
    __bf16* VWB;  // [4][256][256]       bf16  =     524,288 B
    float*  Q;    // alias: YT base
    float*  K;    // alias: YT + 33.5 MB
};

void run_image(const float* x, float* out, int P, int brW, int brH,
               const float* qw, const float* qb, const float* kw, const float* kb,
               const float* vb, const float* sc,
               const Bufs& w, hipStream_t stream)
{
    const int Npix = P * P;
    dim3 blk(256);
    dim3 eg((P / 64) * (P / 64), Bn, 8);

    // ---- half 0: attention over W ----
    qk_proj_kernel<<<dim3(Npix / 128, Bn), blk, 0, stream>>>(
        x, qw + (size_t)brW * C8n * Cn, qb + (size_t)brW * C8n,
        kw + (size_t)brW * C8n * Cn, kb + (size_t)brW * C8n, w.Q, w.K, Npix);
    energy_w_kernel<<<eg, blk, 0, stream>>>(w.Q, w.K, w.E, P, C8n * P / 8);
    if (P == 64) {
        softmax_kernel<64><<<Bn * P, 64, 0, stream>>>(w.E, w.ABF);
        mix_mfma_kernel<64, 64, 256, 0><<<dim3(1, Bn * 64), blk, 0, stream>>>(
            w.ABF, x, w.XH, w.YT);
    } else {
        softmax_kernel<128><<<Bn * P, 64, 0, stream>>>(w.E, w.ABF);
        mix_mfma_kernel<128, 128, 128, 0><<<dim3(2, Bn * 128), blk, 0, stream>>>(
            w.ABF, x, w.XH, w.YT);
    }
    vproj_mfma_kernel<<<dim3(Npix / 128, 2, Bn), blk, 0, stream>>>(
        w.YT, w.VWB + (size_t)brW * Cn * Cn, vb + (size_t)brW * Cn,
        x, out, sc, brW, 1, Npix);

    // ---- half 1: attention over H ----
    transpose_h_kernel<<<dim3((P / 32) * (P / 32), Cn, Bn), blk, 0, stream>>>(
        x, w.XH, P);
    qk_proj_kernel<<<dim3(Npix / 128, Bn), blk, 0, stream>>>(
        x, qw + (size_t)brH * C8n * Cn, qb + (size_t)brH * C8n,
        kw + (size_t)brH * C8n * Cn, kb + (size_t)brH * C8n, w.Q, w.K, Npix);
    energy_h_kernel<<<eg, blk, 0, stream>>>(w.Q, w.K, w.E, P);
    if (P == 64) {
        softmax_kernel<64><<<Bn * P, 64, 0, stream>>>(w.E, w.ABF);
        mix_mfma_kernel<64, 64, 256, 1><<<dim3(1, Bn * 64), blk, 0, stream>>>(
            w.ABF, x, w.XH, w.YT);
    } else {
        softmax_kernel<128><<<Bn * P, 64, 0, stream>>>(w.E, w.ABF);
        mix_mfma_kernel<128, 128, 128, 1><<<dim3(2, Bn * 128), blk, 0, stream>>>(
            w.ABF, x, w.XH, w.YT);
    }
    vproj_mfma_kernel<<<dim3(Npix / 128, 2, Bn), blk, 0, stream>>>(
        w.YT, w.VWB + (size_t)brH * Cn * Cn, vb + (size_t)brH * Cn,
        x, out, sc, brH, 0, Npix);
}

}  // namespace

extern "C" void kernel_launch(void* const* d_in, const int* in_sizes, int n_in,
                              void* d_out, int out_size, void* d_ws, size_t ws_size,
                              hipStream_t stream) {
    (void)in_sizes; (void)n_in; (void)out_size; (void)ws_size;
    const float* tmap = (const float*)d_in[0];
    const float* smap = (const float*)d_in[1];
    const float* qw   = (const float*)d_in[2];
    const float* qb   = (const float*)d_in[3];
    const float* kw   = (const float*)d_in[4];
    const float* kb   = (const float*)d_in[5];
    const float* vw   = (const float*)d_in[6];
    const float* vb   = (const float*)d_in[7];
    const float* sc   = (const float*)d_in[8];

    float* out0 = (float*)d_out;                       // [16,256,64,64]
    float* out1 = out0 + (size_t)16 * 256 * 64 * 64;   // [16,256,128,128]

    // Workspace layout (277,872,640 B total — identical footprint to before).
    char* p = (char*)d_ws;
    Bufs w;
    w.XH  = (__bf16*)p;                 p += (size_t)134217728;
    w.YT  = (__bf16*)p;                 p += (size_t)134217728;
    w.E   = (float*)p;                  p += (size_t)8388608;
    w.ABF = (__bf16*)p;                 p += (size_t)524288;
    w.VWB = (__bf16*)p;                 p += (size_t)524288;
    w.Q   = (float*)w.YT;                               // 33.5 MB
    w.K   = (float*)w.YT + (size_t)16 * 32 * 16384;     // 33.5 MB

    cvt_vw_kernel<<<dim3(256), 256, 0, stream>>>(vw, w.VWB);

    // template: P=64, branches 0 (W) and 2 (H)
    run_image(tmap, out0, 64, 0, 2, qw, qb, kw, kb, vb, sc, w, stream);
    // scene: P=128, branches 1 (W) and 3 (H)
    run_image(smap, out1, 128, 1, 3, qw, qb, kw, kb, vb, sc, w, stream);
}